// Round 1
// baseline (238.061 us; speedup 1.0000x reference)
//
#include <hip/hip_runtime.h>
#include <hip/hip_fp16.h>

#define NB 8
#define NC 128
#define NN 1024
#define NG 8
#define NCG 16
#define GEPS 1e-5f

// Kernel 1: per (b, g, m-tile of 256): compute t = W_g x + b and v = elu(t) into
// LDS (fp16), then max-free softmax-attention over n for each m, shuffle+residual,
// write y to d_out, and atomically accumulate GroupNorm partial sums into d_ws.
__global__ __launch_bounds__(256, 2)
void gsa_attn(const float* __restrict__ points, const float* __restrict__ w,
              const float* __restrict__ bias, float* __restrict__ y,
              float* __restrict__ stats)
{
    __shared__ __half t_lds[NN][NCG];  // 32 KB
    __shared__ __half v_lds[NN][NCG];  // 32 KB

    const int tid = threadIdx.x;
    const int bid = blockIdx.x;
    const int mt  = bid & 3;          // m-tile
    const int g   = (bid >> 2) & 7;   // group
    const int b   = bid >> 5;         // batch

    const float* xg = points + ((size_t)(b * NC) + g * NCG) * NN; // x[i][n] = xg[i*NN+n]
    const float* wg = w + g * NCG * NCG;                          // wg[o*NCG+i]

    // ---- phase 1: t and v=elu(t) into LDS (full 1024 columns) ----
    for (int k = 0; k < 4; ++k) {
        const int n = (k << 8) + tid;
        float x[NCG];
        #pragma unroll
        for (int i = 0; i < NCG; ++i) x[i] = xg[(size_t)i * NN + n];
        #pragma unroll
        for (int o = 0; o < NCG; ++o) {
            float acc = bias[g * NCG + o];
            #pragma unroll
            for (int i = 0; i < NCG; ++i) acc = fmaf(wg[o * NCG + i], x[i], acc);
            t_lds[n][o] = __float2half(acc);
            const float ve = acc > 0.f ? acc : (__expf(acc) - 1.f);
            v_lds[n][o] = __float2half(ve);
        }
    }
    __syncthreads();

    // ---- phase 2: attention for column m = mt*256 + tid ----
    const int m = (mt << 8) + tid;
    float q[NCG];
    #pragma unroll
    for (int c = 0; c < NCG; ++c) q[c] = __half2float(t_lds[m][c]);

    float acc[NCG];
    #pragma unroll
    for (int c = 0; c < NCG; ++c) acc[c] = 0.f;
    float ssum = 0.f;

    // max-free softmax: s[m,m] >= 0 guarantees column max >= 0, so exp(s-20)
    // can neither overflow nor underflow the denominator.
    #pragma unroll 2
    for (int n = 0; n < NN; ++n) {
        float s = 0.f;
        #pragma unroll
        for (int c = 0; c < NCG; ++c)
            s = fmaf(q[c], __half2float(t_lds[n][c]), s);
        s = fminf(s * 0.25f - 20.0f, 60.0f);
        const float p = __expf(s);
        ssum += p;
        #pragma unroll
        for (int c = 0; c < NCG; ++c)
            acc[c] = fmaf(p, __half2float(v_lds[n][c]), acc[c]);
    }

    // ---- phase 3: normalize, shuffle, residual, write y, GN partial sums ----
    const float rs = 1.0f / ssum;
    float sm[NG], sq[NG];
    #pragma unroll
    for (int j = 0; j < NG; ++j) { sm[j] = 0.f; sq[j] = 0.f; }

    #pragma unroll
    for (int c = 0; c < NCG; ++c) {
        // channel shuffle: c_new = c*G + g
        const size_t oidx = ((size_t)(b * NC) + (c * NG + g)) * NN + m;
        const float val = acc[c] * rs + points[oidx];
        y[oidx] = val;
        sm[c >> 1] += val;         // post-shuffle group g' = c_new>>4 = c>>1
        sq[c >> 1] += val * val;
    }

    // wave-level butterfly reduce (64 lanes), then one atomic per wave
    #pragma unroll
    for (int j = 0; j < NG; ++j) {
        float a = sm[j], bq = sq[j];
        #pragma unroll
        for (int off = 32; off > 0; off >>= 1) {
            a  += __shfl_xor(a, off);
            bq += __shfl_xor(bq, off);
        }
        sm[j] = a; sq[j] = bq;
    }
    if ((tid & 63) == 0) {
        #pragma unroll
        for (int j = 0; j < NG; ++j) {
            atomicAdd(&stats[(b * NG + j) * 2 + 0], sm[j]);
            atomicAdd(&stats[(b * NG + j) * 2 + 1], sq[j]);
        }
    }
}

// Kernel 2: GroupNorm finalize, in place on y (d_out), vectorized float4.
__global__ __launch_bounds__(256)
void gsa_norm(const float* __restrict__ stats, const float* __restrict__ gamma,
              const float* __restrict__ beta, float* __restrict__ y)
{
    const int idx = blockIdx.x * 256 + threadIdx.x;   // B*C*N/4 threads
    const size_t base = (size_t)idx * 4;
    const int c = (int)((base >> 10) & (NC - 1));     // /N % C
    const int b = (int)(base >> 17);                  // /(C*N)
    const int gp = c >> 4;

    const float s0 = stats[(b * NG + gp) * 2 + 0];
    const float s1 = stats[(b * NG + gp) * 2 + 1];
    const float inv = 1.0f / (float)(NCG * NN);
    const float mean = s0 * inv;
    const float var = fmaxf(s1 * inv - mean * mean, 0.f);
    const float sc = rsqrtf(var + GEPS) * gamma[c];
    const float sh = fmaf(-mean, sc, beta[c]);

    float4 v = *reinterpret_cast<const float4*>(y + base);
    v.x = fmaf(v.x, sc, sh);
    v.y = fmaf(v.y, sc, sh);
    v.z = fmaf(v.z, sc, sh);
    v.w = fmaf(v.w, sc, sh);
    *reinterpret_cast<float4*>(y + base) = v;
}

extern "C" void kernel_launch(void* const* d_in, const int* in_sizes, int n_in,
                              void* d_out, int out_size, void* d_ws, size_t ws_size,
                              hipStream_t stream)
{
    const float* points = (const float*)d_in[0];
    const float* w      = (const float*)d_in[1];
    const float* bias   = (const float*)d_in[2];
    const float* gamma  = (const float*)d_in[3];
    const float* beta   = (const float*)d_in[4];
    float* y     = (float*)d_out;
    float* stats = (float*)d_ws;   // B*G*2 floats = 512 B

    hipMemsetAsync(stats, 0, NB * NG * 2 * sizeof(float), stream);
    gsa_attn<<<NB * NG * 4, 256, 0, stream>>>(points, w, bias, y, stats);
    gsa_norm<<<(NB * NC * NN / 4) / 256, 256, 0, stream>>>(stats, gamma, beta, y);
}

// Round 2
// 139.291 us; speedup vs baseline: 1.7091x; 1.7091x over previous
//
#include <hip/hip_runtime.h>
#include <hip/hip_fp16.h>
#include <hip/hip_cooperative_groups.h>

namespace cg = cooperative_groups;

#define NB 8
#define NC 128
#define NN 1024
#define NG 8
#define NCG 16
#define GEPS 1e-5f
#define TPAD 20    // f16 per t-row (16 + 4 pad), row = 40 B, 8-aligned
#define VROW 1032  // bf16 per v-row (1024 + 8 pad), row = 2064 B, 8-aligned

typedef _Float16 half4v __attribute__((ext_vector_type(4)));
typedef short short4v __attribute__((ext_vector_type(4)));
typedef float float4v __attribute__((ext_vector_type(4)));
typedef unsigned int uint2v __attribute__((ext_vector_type(2)));

// One WG per (b, g, m-quarter): conv -> LDS, MFMA attention, residual+shuffle,
// GN stats via atomics, grid-wide sync, GN finalize. 256 WGs = 1 per CU.
__global__ __launch_bounds__(512)
void gsa_fused(const float* __restrict__ points, const float* __restrict__ w,
               const float* __restrict__ bias, const float* __restrict__ gamma,
               const float* __restrict__ beta, float* __restrict__ y,
               float* __restrict__ stats)
{
    __shared__ __align__(16) _Float16 t_lds[NN][TPAD];        // t * 0.5 (folds 1/sqrt(16))
    __shared__ __align__(16) unsigned short v_lds[NCG][VROW]; // elu(t) as bf16 bits

    const int tid = threadIdx.x;
    const int bid = blockIdx.x;
    const int mq  = bid & 3;
    const int g   = (bid >> 2) & 7;
    const int b   = bid >> 5;

    const float* xg = points + ((size_t)(b * NC) + g * NCG) * NN;
    const float* wg = w + g * NCG * NCG;

    // ---- phase 1: grouped 1x1 conv; t (f16, x0.5) n-major, v=elu(t) (bf16) c-major
    #pragma unroll
    for (int k = 0; k < 2; ++k) {
        const int n = (k << 9) + tid;
        float x[NCG];
        #pragma unroll
        for (int i = 0; i < NCG; ++i) x[i] = xg[(size_t)i * NN + n];
        _Float16 trow[NCG];
        #pragma unroll
        for (int o = 0; o < NCG; ++o) {
            float acc = bias[g * NCG + o];
            #pragma unroll
            for (int i = 0; i < NCG; ++i) acc = fmaf(wg[o * NCG + i], x[i], acc);
            trow[o] = (_Float16)(acc * 0.5f);
            const float ve = acc > 0.f ? acc : (__expf(acc) - 1.f);
            const unsigned int u = __builtin_bit_cast(unsigned int, ve);
            v_lds[o][n] = (unsigned short)((u + 0x8000u) >> 16);  // f32 -> bf16 (round-half-up)
        }
        #pragma unroll
        for (int q = 0; q < 4; ++q)
            *(half4v*)&t_lds[n][q * 4] = *(const half4v*)&trow[q * 4];
    }
    __syncthreads();

    // ---- phase 2: attention. Wave owns 32 m-cols (2 MFMA tiles).
    const int lane = tid & 63;
    const int wv   = tid >> 6;          // 0..7
    const int lq   = lane & 15;
    const int lh   = lane >> 4;         // 0..3
    const int mw   = (mq << 8) + (wv << 5);

    // Q-side B fragments (loop-invariant): B[k=c][j=m], lane: c=4*lh+j, m=base+lq
    const half4v bfrag0 = *(const half4v*)&t_lds[mw + lq][lh * 4];
    const half4v bfrag1 = *(const half4v*)&t_lds[mw + 16 + lq][lh * 4];

    float4v acc0 = {0.f, 0.f, 0.f, 0.f}, acc1 = {0.f, 0.f, 0.f, 0.f};
    float ssum0 = 0.f, ssum1 = 0.f;
    const float4v zz = {0.f, 0.f, 0.f, 0.f};

    #pragma unroll 4
    for (int nt = 0; nt < NN; nt += 16) {
        // K-side A frag: A[i=n][k=c], lane: n=nt+lq, c=4*lh+j
        const half4v afrag = *(const half4v*)&t_lds[nt + lq][lh * 4];
        // V frag (PV A operand): A[i=c][k=n], lane: c=lq, n=nt+4*lh+j
        const short4v vfrag = *(const short4v*)&v_lds[lq][nt + lh * 4];

        // S[n,m] = dot(t,t)/4 ; D reg r: row n=nt+4*lh+r, col m=base+lq
        float4v s0 = __builtin_amdgcn_mfma_f32_16x16x16f16(afrag, bfrag0, zz, 0, 0, 0);
        float4v s1 = __builtin_amdgcn_mfma_f32_16x16x16f16(afrag, bfrag1, zz, 0, 0, 0);

        float p0[4], p1[4];
        #pragma unroll
        for (int r = 0; r < 4; ++r) { p0[r] = __expf(s0[r]); p1[r] = __expf(s1[r]); }
        ssum0 += (p0[0] + p0[1]) + (p0[2] + p0[3]);
        ssum1 += (p1[0] + p1[1]) + (p1[2] + p1[3]);

        // P -> bf16; S D-layout == PV B-fragment layout (reg r <-> k), no LDS round-trip
        unsigned int pk00, pk01, pk10, pk11;
        asm("v_cvt_pk_bf16_f32 %0, %1, %2" : "=v"(pk00) : "v"(p0[0]), "v"(p0[1]));
        asm("v_cvt_pk_bf16_f32 %0, %1, %2" : "=v"(pk01) : "v"(p0[2]), "v"(p0[3]));
        asm("v_cvt_pk_bf16_f32 %0, %1, %2" : "=v"(pk10) : "v"(p1[0]), "v"(p1[1]));
        asm("v_cvt_pk_bf16_f32 %0, %1, %2" : "=v"(pk11) : "v"(p1[2]), "v"(p1[3]));
        uint2v u0; u0[0] = pk00; u0[1] = pk01;
        uint2v u1; u1[0] = pk10; u1[1] = pk11;

        acc0 = __builtin_amdgcn_mfma_f32_16x16x16bf16_1k(vfrag, __builtin_bit_cast(short4v, u0), acc0, 0, 0, 0);
        acc1 = __builtin_amdgcn_mfma_f32_16x16x16bf16_1k(vfrag, __builtin_bit_cast(short4v, u1), acc1, 0, 0, 0);
    }

    // full column sums (reduce over the 4 row-groups)
    ssum0 += __shfl_xor(ssum0, 16); ssum0 += __shfl_xor(ssum0, 32);
    ssum1 += __shfl_xor(ssum1, 16); ssum1 += __shfl_xor(ssum1, 32);
    const float rs0 = 1.0f / ssum0, rs1 = 1.0f / ssum1;

    // ---- phase 3: residual + channel shuffle + GN partial sums
    float vals[2][4];
    float gs[2] = {0.f, 0.f}, gq[2] = {0.f, 0.f};
    #pragma unroll
    for (int mt = 0; mt < 2; ++mt) {
        const float rs = mt ? rs1 : rs0;
        const int m = mw + mt * 16 + lq;
        #pragma unroll
        for (int r = 0; r < 4; ++r) {
            const int c = lh * 4 + r;                                  // pre-shuffle channel
            const size_t oi = ((size_t)(b * NC) + (c * NG + g)) * NN + m;
            const float a = mt ? acc1[r] : acc0[r];
            const float val = fmaf(a, rs, points[oi]);
            vals[mt][r] = val;
            gs[r >> 1] += val;            // post-shuffle GN group = 2*lh + (r>>1)
            gq[r >> 1] += val * val;
        }
    }
    #pragma unroll
    for (int j = 0; j < 2; ++j) {
        float a = gs[j], q = gq[j];
        #pragma unroll
        for (int off = 1; off <= 8; off <<= 1) {  // reduce over 16 lq lanes
            a += __shfl_xor(a, off);
            q += __shfl_xor(q, off);
        }
        if (lq == 0) {
            atomicAdd(&stats[(b * NG + lh * 2 + j) * 2 + 0], a);
            atomicAdd(&stats[(b * NG + lh * 2 + j) * 2 + 1], q);
        }
    }

    cg::this_grid().sync();

    // ---- phase 4: GroupNorm finalize (vals still in registers)
    const float inv = 1.0f / (float)(NCG * NN);
    float mean[2], rstd[2];
    #pragma unroll
    for (int j = 0; j < 2; ++j) {
        const float s0 = stats[(b * NG + lh * 2 + j) * 2 + 0];
        const float s1 = stats[(b * NG + lh * 2 + j) * 2 + 1];
        mean[j] = s0 * inv;
        const float var = fmaxf(s1 * inv - mean[j] * mean[j], 0.f);
        rstd[j] = rsqrtf(var + GEPS);
    }
    #pragma unroll
    for (int mt = 0; mt < 2; ++mt) {
        const int m = mw + mt * 16 + lq;
        #pragma unroll
        for (int r = 0; r < 4; ++r) {
            const int c  = lh * 4 + r;
            const int cn = c * NG + g;
            const size_t oi = ((size_t)(b * NC) + cn) * NN + m;
            const int j = r >> 1;
            y[oi] = fmaf(vals[mt][r] - mean[j], rstd[j] * gamma[cn], beta[cn]);
        }
    }
}

extern "C" void kernel_launch(void* const* d_in, const int* in_sizes, int n_in,
                              void* d_out, int out_size, void* d_ws, size_t ws_size,
                              hipStream_t stream)
{
    const float* points = (const float*)d_in[0];
    const float* w      = (const float*)d_in[1];
    const float* bias   = (const float*)d_in[2];
    const float* gamma  = (const float*)d_in[3];
    const float* beta   = (const float*)d_in[4];
    float* y     = (float*)d_out;
    float* stats = (float*)d_ws;   // B*G*2 floats = 512 B

    hipMemsetAsync(stats, 0, NB * NG * 2 * sizeof(float), stream);

    void* args[] = { (void*)&points, (void*)&w, (void*)&bias, (void*)&gamma,
                     (void*)&beta, (void*)&y, (void*)&stats };
    hipLaunchCooperativeKernel((const void*)gsa_fused, dim3(NB * NG * 4), dim3(512),
                               args, 0, stream);
}

// Round 5
// 104.775 us; speedup vs baseline: 2.2721x; 1.3294x over previous
//
#include <hip/hip_runtime.h>
#include <hip/hip_fp16.h>

#define NB 8
#define NC 128
#define NN 1024
#define NG 8
#define NCG 16
#define GEPS 1e-5f
#define TPAD 20    // f16 per t-row (16 + 4 pad), row = 40 B, 8-aligned
#define VROW 1032  // bf16 per v-row (1024 + 8 pad), row = 2064 B, 8-aligned

typedef _Float16 half4v __attribute__((ext_vector_type(4)));
typedef short short4v __attribute__((ext_vector_type(4)));
typedef float float4v __attribute__((ext_vector_type(4)));
typedef unsigned int uint2v __attribute__((ext_vector_type(2)));

// Round-2's validated attention kernel body (512 threads, 1 WG/CU), with the
// only change being: write UNNORMALIZED y in phase 3 and hand GN finalize to a
// separate kernel (round-1-validated split) instead of grid.sync + phase 4.
__global__ __launch_bounds__(512)
void gsa_attn(const float* __restrict__ points, const float* __restrict__ w,
              const float* __restrict__ bias, float* __restrict__ y,
              float* __restrict__ stats)
{
    __shared__ __align__(16) _Float16 t_lds[NN][TPAD];        // t * 0.5 (folds 1/sqrt(16))
    __shared__ __align__(16) unsigned short v_lds[NCG][VROW]; // elu(t) as bf16 bits

    const int tid = threadIdx.x;
    const int bid = blockIdx.x;
    const int mq  = bid & 3;
    const int g   = (bid >> 2) & 7;
    const int b   = bid >> 5;

    const float* xg = points + ((size_t)(b * NC) + g * NCG) * NN;
    const float* wg = w + g * NCG * NCG;

    // ---- phase 1: grouped 1x1 conv; t (f16, x0.5) n-major, v=elu(t) (bf16) c-major
    #pragma unroll
    for (int k = 0; k < 2; ++k) {
        const int n = (k << 9) + tid;
        float x[NCG];
        #pragma unroll
        for (int i = 0; i < NCG; ++i) x[i] = xg[(size_t)i * NN + n];
        _Float16 trow[NCG];
        #pragma unroll
        for (int o = 0; o < NCG; ++o) {
            float acc = bias[g * NCG + o];
            #pragma unroll
            for (int i = 0; i < NCG; ++i) acc = fmaf(wg[o * NCG + i], x[i], acc);
            trow[o] = (_Float16)(acc * 0.5f);
            const float ve = acc > 0.f ? acc : (__expf(acc) - 1.f);
            const unsigned int u = __builtin_bit_cast(unsigned int, ve);
            v_lds[o][n] = (unsigned short)((u + 0x8000u) >> 16);  // f32 -> bf16 (round-half-up)
        }
        #pragma unroll
        for (int q = 0; q < 4; ++q)
            *(half4v*)&t_lds[n][q * 4] = *(const half4v*)&trow[q * 4];
    }
    __syncthreads();

    // ---- phase 2: attention. Wave owns 32 m-cols (2 MFMA tiles).
    const int lane = tid & 63;
    const int wv   = tid >> 6;          // 0..7
    const int lq   = lane & 15;
    const int lh   = lane >> 4;         // 0..3
    const int mw   = (mq << 8) + (wv << 5);

    const half4v bfrag0 = *(const half4v*)&t_lds[mw + lq][lh * 4];
    const half4v bfrag1 = *(const half4v*)&t_lds[mw + 16 + lq][lh * 4];

    float4v acc0 = {0.f, 0.f, 0.f, 0.f}, acc1 = {0.f, 0.f, 0.f, 0.f};
    float ssum0 = 0.f, ssum1 = 0.f;
    const float4v zz = {0.f, 0.f, 0.f, 0.f};

    #pragma unroll 4
    for (int nt = 0; nt < NN; nt += 16) {
        const half4v afrag = *(const half4v*)&t_lds[nt + lq][lh * 4];
        const short4v vfrag = *(const short4v*)&v_lds[lq][nt + lh * 4];

        float4v s0 = __builtin_amdgcn_mfma_f32_16x16x16f16(afrag, bfrag0, zz, 0, 0, 0);
        float4v s1 = __builtin_amdgcn_mfma_f32_16x16x16f16(afrag, bfrag1, zz, 0, 0, 0);

        float p0[4], p1[4];
        #pragma unroll
        for (int r = 0; r < 4; ++r) { p0[r] = __expf(s0[r]); p1[r] = __expf(s1[r]); }
        ssum0 += (p0[0] + p0[1]) + (p0[2] + p0[3]);
        ssum1 += (p1[0] + p1[1]) + (p1[2] + p1[3]);

        unsigned int pk00, pk01, pk10, pk11;
        asm("v_cvt_pk_bf16_f32 %0, %1, %2" : "=v"(pk00) : "v"(p0[0]), "v"(p0[1]));
        asm("v_cvt_pk_bf16_f32 %0, %1, %2" : "=v"(pk01) : "v"(p0[2]), "v"(p0[3]));
        asm("v_cvt_pk_bf16_f32 %0, %1, %2" : "=v"(pk10) : "v"(p1[0]), "v"(p1[1]));
        asm("v_cvt_pk_bf16_f32 %0, %1, %2" : "=v"(pk11) : "v"(p1[2]), "v"(p1[3]));
        uint2v u0; u0[0] = pk00; u0[1] = pk01;
        uint2v u1; u1[0] = pk10; u1[1] = pk11;

        acc0 = __builtin_amdgcn_mfma_f32_16x16x16bf16_1k(vfrag, __builtin_bit_cast(short4v, u0), acc0, 0, 0, 0);
        acc1 = __builtin_amdgcn_mfma_f32_16x16x16bf16_1k(vfrag, __builtin_bit_cast(short4v, u1), acc1, 0, 0, 0);
    }

    ssum0 += __shfl_xor(ssum0, 16); ssum0 += __shfl_xor(ssum0, 32);
    ssum1 += __shfl_xor(ssum1, 16); ssum1 += __shfl_xor(ssum1, 32);
    const float rs0 = 1.0f / ssum0, rs1 = 1.0f / ssum1;

    // ---- phase 3: residual + channel shuffle + unnormalized y + GN partials
    float gs[2] = {0.f, 0.f}, gq[2] = {0.f, 0.f};
    #pragma unroll
    for (int mt = 0; mt < 2; ++mt) {
        const float rs = mt ? rs1 : rs0;
        const int m = mw + mt * 16 + lq;
        #pragma unroll
        for (int r = 0; r < 4; ++r) {
            const int c = lh * 4 + r;
            const size_t oi = ((size_t)(b * NC) + (c * NG + g)) * NN + m;
            const float a = mt ? acc1[r] : acc0[r];
            const float val = fmaf(a, rs, points[oi]);
            y[oi] = val;
            gs[r >> 1] += val;            // post-shuffle GN group g' = 2*lh + (r>>1)
            gq[r >> 1] += val * val;
        }
    }
    #pragma unroll
    for (int j = 0; j < 2; ++j) {
        float a = gs[j], q = gq[j];
        #pragma unroll
        for (int off = 1; off <= 8; off <<= 1) {   // reduce over the 16 lq lanes
            a += __shfl_xor(a, off);
            q += __shfl_xor(q, off);
        }
        if (lq == 0) {
            atomicAdd(&stats[(b * NG + lh * 2 + j) * 2 + 0], a);
            atomicAdd(&stats[(b * NG + lh * 2 + j) * 2 + 1], q);
        }
    }
}

// Kernel 2: GroupNorm finalize, in place on y, float4 (round-1-validated).
__global__ __launch_bounds__(256)
void gsa_norm(const float* __restrict__ stats, const float* __restrict__ gamma,
              const float* __restrict__ beta, float* __restrict__ y)
{
    const int idx = blockIdx.x * 256 + threadIdx.x;
    const size_t base = (size_t)idx * 4;
    const int c = (int)((base >> 10) & (NC - 1));
    const int b = (int)(base >> 17);
    const int gp = c >> 4;

    const float s0 = stats[(b * NG + gp) * 2 + 0];
    const float s1 = stats[(b * NG + gp) * 2 + 1];
    const float inv = 1.0f / (float)(NCG * NN);
    const float mean = s0 * inv;
    const float var = fmaxf(s1 * inv - mean * mean, 0.f);
    const float sc = rsqrtf(var + GEPS) * gamma[c];
    const float sh = fmaf(-mean, sc, beta[c]);

    float4 v = *reinterpret_cast<const float4*>(y + base);
    v.x = fmaf(v.x, sc, sh);
    v.y = fmaf(v.y, sc, sh);
    v.z = fmaf(v.z, sc, sh);
    v.w = fmaf(v.w, sc, sh);
    *reinterpret_cast<float4*>(y + base) = v;
}

extern "C" void kernel_launch(void* const* d_in, const int* in_sizes, int n_in,
                              void* d_out, int out_size, void* d_ws, size_t ws_size,
                              hipStream_t stream)
{
    const float* points = (const float*)d_in[0];
    const float* w      = (const float*)d_in[1];
    const float* bias   = (const float*)d_in[2];
    const float* gamma  = (const float*)d_in[3];
    const float* beta   = (const float*)d_in[4];
    float* y     = (float*)d_out;
    float* stats = (float*)d_ws;   // B*G*2 floats = 512 B

    hipMemsetAsync(stats, 0, NB * NG * 2 * sizeof(float), stream);
    gsa_attn<<<NB * NG * 4, 512, 0, stream>>>(points, w, bias, y, stats);
    gsa_norm<<<NB * NC * NN / 4 / 256, 256, 0, stream>>>(stats, gamma, beta, y);
}